// Round 1
// baseline (299.662 us; speedup 1.0000x reference)
//
#include <hip/hip_runtime.h>

#define T_LEN 2048
#define NMODE 8
#define NPP   17   // 8 tau + 9 g (g[0]=g_infy)

// ===========================================================================
// Fused single-kernel viscoelastic stress update.
//
// Each block = one 128-step tile (G=8 chunks x L=16) of one batch row b.
// In-block: stage inputs -> coeff pass -> concurrent {72-thread chunk scans,
// 64-thread cumA} -> in-block cross-chunk compose -> publish tile aggregate
// (P[8], R[9][8]) to a device-scope spine -> decoupled lookback over <=15
// predecessor aggregates -> finalize all three output planes coalesced.
//
// No caA/qsum/S_infy/partR HBM round-trips; all intermediate state is LDS.
// Progress guarantee: atomic ticket assigns tile-major virtual ids, so any
// spinning block waits only on earlier tickets (already resident/finished).
// Replay safety: hipMemsetAsync clears ticket+flags per launch; vid modulo
// keeps an un-reset replay in-range (stale flags then point at identical
// deterministic payloads -> still correct).
// ===========================================================================
template <int L, int G>
__global__ __launch_bounds__(256)
void fused(const float* __restrict__ Se,   // [B,T,3,3]
           const float* __restrict__ tt,   // [B,T]
           const float* __restrict__ pp,   // [B,T,17]
           float* __restrict__ out,        // [3,B,T,3,3]
           float* __restrict__ spine,      // [B*TILES][80]  P[8] then R[72]
           unsigned* __restrict__ flags,   // [B*TILES]
           unsigned* __restrict__ ticket,
           int B) {
    constexpr int NSTEP = G * L;            // 128
    constexpr int TILES = T_LEN / NSTEP;    // 16
    constexpr int RW    = NSTEP + 1;        // 129
    constexpr int NT    = 256;
    constexpr int RAW_SZ = RW * NPP;                 // 2193
    constexpr int SROW   = NSTEP + 4;                // 132
    constexpr int QT_SZ  = 9 * SROW;                 // 1188
    constexpr int CA_K   = L * 8 + 4;                // 132
    constexpr int UNION_SZ = (RAW_SZ > QT_SZ + G * CA_K) ? RAW_SZ
                                                         : (QT_SZ + G * CA_K);
    constexpr int AC_K  = L * 16 + 4;                // 260
    constexpr int O_AC  = UNION_SZ;                  // AC | {Zrel,Pp,Z} overlay
    constexpr int O_RP  = O_AC + G * AC_K;           // s_R (576) + s_P (64)
    constexpr int O_ST  = O_RP + G * 72 + G * 8;
    constexpr int O_T   = O_ST + 9 * SROW;
    constexpr int O_INV = O_T + RW;
    constexpr int O_GI  = O_INV + RW;
    constexpr int TOTAL = O_GI + RW;
    static_assert(L == 16, "epilogue uses t>>4 / t&15");
    static_assert(G * 72 + G * 8 + G * 72 <= G * AC_K, "overlay fits in AC");

    __shared__ __align__(16) float sm[TOTAL];
    float* s_raw  = sm;                      // union: raw inputs
    float* s_qT   = sm;                      // union: qsum transposed [e][t]
    float* s_ca   = sm + QT_SZ;              // union: cumA skewed [k][s][8]
    float* s_AC   = sm + O_AC;               // coeffs (dead after phase 2)
    float* s_Zrel = sm + O_AC;               // overlay: chunk-relative prefix
    float* s_Pp   = sm + O_AC + G * 72;      // overlay: chunk prefix products
    float* s_Z    = sm + O_AC + G * 72 + G * 8;  // overlay: entering states
    float* s_R    = sm + O_RP;               // chunk-local results [k][e][m]
    float* s_P    = sm + O_RP + G * 72;      // chunk A-products   [k][m]
    float* s_ST   = sm + O_ST;
    float* s_t    = sm + O_T;
    float* s_inv  = sm + O_INV;
    float* s_gi   = sm + O_GI;

    const int tid = threadIdx.x;

    // ---- ticket: tile-major virtual id ----
    __shared__ unsigned s_vid;
    if (tid == 0) s_vid = atomicAdd(ticket, 1u);
    __syncthreads();
    const int vid  = (int)(s_vid % (unsigned)(B * TILES));
    const int tile = vid / B;     // all dependencies have strictly lower vid
    const int b    = vid % B;

    const int base = tile * NSTEP;
    const int off  = (base == 0) ? 0 : 1;
    const int r0   = (base == 0) ? 0 : base - 1;

    // ---- stage inputs ----
    {
        const float* pr = pp + ((size_t)b * T_LEN + r0) * NPP;
        for (int i = tid; i < RW * NPP; i += NT) s_raw[i] = pr[i];
        const float* sr = Se + ((size_t)b * T_LEN + r0) * 9;
        for (int i = tid; i < RW * 9; i += NT) {
            int r = i / 9, e = i - r * 9;
            s_ST[e * SROW + r] = sr[i];
        }
        const float* tr = tt + (size_t)b * T_LEN + r0;
        for (int i = tid; i < RW; i += NT) s_t[i] = tr[i];
    }
    __syncthreads();

    // ---- per-row 1/sum(g), g_infy/sum ----
    for (int i = tid; i < RW; i += NT) {
        float gs = 0.f;
        #pragma unroll
        for (int k = 8; k < NPP; ++k) gs += s_raw[i * NPP + k];
        float iv = __builtin_amdgcn_rcpf(gs);
        s_inv[i] = iv;
        s_gi[i]  = s_raw[i * NPP + 8] * iv;
    }
    __syncthreads();

    // ---- per-(step,mode) coefficients: all exp/rcp here ----
    for (int i = tid; i < NSTEP * 8; i += NT) {
        int m  = i & 7;
        int ts = i >> 3;
        int rc = ts + off;
        bool first = (base == 0) && (ts == 0);
        int rp = first ? rc : rc - 1;
        float tau_c = s_raw[rc * NPP + m];
        float tau_p = s_raw[rp * NPP + m];
        float gqh_c = 0.5f * s_raw[rc * NPP + 9 + m] * s_inv[rc];
        float gqh_p = 0.5f * s_raw[rp * NPP + 9 + m] * s_inv[rp];
        float t_c = s_t[rc];
        float t_p = first ? -s_t[1] : s_t[rp];
        float ee  = __expf((t_p - t_c) * __builtin_amdgcn_rcpf(tau_c + tau_p));
        int kk = ts / L, sl = ts % L;
        s_AC[kk * AC_K + sl * 16 + m]     = ee * ee;              // A
        s_AC[kk * AC_K + sl * 16 + 8 + m] = ee * (gqh_c + gqh_p); // C
    }
    __syncthreads();   // s_raw consumed; union becomes s_qT/s_ca

    // ---- phase 2: concurrent chunk scans + cumA ----
    if (tid < 72) {
        const int k = tid / 9;
        const int e = tid - k * 9;

        float dS[L];
        {
            float Sv[L + 1];
            Sv[0] = (base == 0 && k == 0)
                        ? 0.f
                        : s_ST[e * SROW + (k * L + off - 1)];
            #pragma unroll
            for (int s = 0; s < L; ++s)
                Sv[s + 1] = s_ST[e * SROW + (k * L + s + off)];
            #pragma unroll
            for (int s = 0; s < L; ++s) dS[s] = Sv[s + 1] - Sv[s];
        }

        float Q[8] = {0,0,0,0,0,0,0,0};
        const float4* acp = (const float4*)(s_AC + k * AC_K);

        float4 a0 = acp[0], a1 = acp[1], c0v = acp[2], c1v = acp[3];
        #pragma unroll
        for (int s = 0; s < L; ++s) {
            float4 na0, na1, nc0, nc1;
            if (s < L - 1) {
                na0 = acp[4*s+4]; na1 = acp[4*s+5];
                nc0 = acp[4*s+6]; nc1 = acp[4*s+7];
            }
            float d = dS[s];
            Q[0] = a0.x*Q[0] + c0v.x*d;  Q[1] = a0.y*Q[1] + c0v.y*d;
            Q[2] = a0.z*Q[2] + c0v.z*d;  Q[3] = a0.w*Q[3] + c0v.w*d;
            Q[4] = a1.x*Q[4] + c1v.x*d;  Q[5] = a1.y*Q[5] + c1v.y*d;
            Q[6] = a1.z*Q[6] + c1v.z*d;  Q[7] = a1.w*Q[7] + c1v.w*d;
            float qs = ((Q[0]+Q[1])+(Q[2]+Q[3])) + ((Q[4]+Q[5])+(Q[6]+Q[7]));
            s_qT[e * SROW + (k * L + s)] = qs;
            a0 = na0; a1 = na1; c0v = nc0; c1v = nc1;
        }

        float4* r4 = (float4*)(s_R + (k * 72 + e * 8));
        r4[0] = make_float4(Q[0], Q[1], Q[2], Q[3]);
        r4[1] = make_float4(Q[4], Q[5], Q[6], Q[7]);
    } else if (tid >= 192) {
        // ---- threads 192..255 = (k,m): cumA + chunk product ----
        const int u = tid - 192;
        const int k = u >> 3;
        const int m = u & 7;
        float c = 1.f;
        #pragma unroll
        for (int s = 0; s < L; ++s) {
            c *= s_AC[k * AC_K + s * 16 + m];
            s_ca[k * CA_K + s * 8 + m] = c;
        }
        s_P[u] = c;
    }
    __syncthreads();

    // ---- phase 3: in-block cross-chunk compose (72 threads = (e,m)) ----
    if (tid < 72) {
        const int e = tid >> 3;
        const int m = tid & 7;
        float z = 0.f, pprod = 1.f;
        #pragma unroll
        for (int k = 0; k < G; ++k) {
            s_Zrel[k * 72 + tid] = z;
            if (e == 0) s_Pp[k * 8 + m] = pprod;
            float Pk = s_P[k * 8 + m];
            z = Pk * z + s_R[k * 72 + tid];
            pprod *= Pk;
        }
        if (tile != TILES - 1) {   // last tile has no consumers
            float* sp = spine + ((size_t)b * TILES + tile) * 80;
            sp[8 + tid] = z;           // R_tile[e][m]
            if (e == 0) sp[m] = pprod; // P_tile[m]
        }
    }
    __syncthreads();

    // ---- publish aggregate (decoupled: before our own lookback) ----
    if (tile != TILES - 1 && tid == 0) {
        __threadfence();
        __hip_atomic_store(&flags[(size_t)b * TILES + tile], 1u,
                           __ATOMIC_RELEASE, __HIP_MEMORY_SCOPE_AGENT);
    }

    // ---- phase 4: lookback over predecessor aggregates ----
    float zin = 0.f;
    {
        const int e = tid >> 3;
        const int m = tid & 7;
        for (int j = 0; j < tile; ++j) {
            if (tid == 0) {
                while (__hip_atomic_load(&flags[(size_t)b * TILES + j],
                                         __ATOMIC_ACQUIRE,
                                         __HIP_MEMORY_SCOPE_AGENT) == 0u)
                    __builtin_amdgcn_s_sleep(2);
            }
            __syncthreads();
            if (tid < 72) {
                float* sp = spine + ((size_t)b * TILES + j) * 80;
                float Pj = __hip_atomic_load(sp + m, __ATOMIC_RELAXED,
                                             __HIP_MEMORY_SCOPE_AGENT);
                float Rj = __hip_atomic_load(sp + 8 + tid, __ATOMIC_RELAXED,
                                             __HIP_MEMORY_SCOPE_AGENT);
                zin = Pj * zin + Rj;
            }
        }
    }

    // ---- phase 5: entering state per chunk ----
    if (tid < 72) {
        const int m = tid & 7;
        #pragma unroll
        for (int k = 0; k < G; ++k)
            s_Z[k * 72 + tid] = s_Pp[k * 8 + m] * zin + s_Zrel[k * 72 + tid];
    }
    __syncthreads();

    // ---- phase 6: finalize all three planes, coalesced float4 ----
    const size_t nOut = (size_t)B * T_LEN * 9;
    float* o0 = out + ((size_t)b * T_LEN + base) * 9;
    float* o1 = o0 + nOut;
    float* o2 = o0 + 2 * nOut;
    for (int i4 = tid; i4 < NSTEP * 9 / 4; i4 += NT) {
        int i = i4 * 4;
        float q[4], f[4];
        #pragma unroll
        for (int j = 0; j < 4; ++j) {
            int idx = i + j;
            int t = idx / 9, e = idx - t * 9;
            int rc = t + off;
            int k = t >> 4, s = t & 15;
            const float* caT = &s_ca[k * CA_K + s * 8];
            const float* zE  = &s_Z[k * 72 + e * 8];
            float cr = 0.f;
            #pragma unroll
            for (int m = 0; m < NMODE; ++m) cr += caT[m] * zE[m];
            q[j] = s_qT[e * SROW + t] + cr;
            f[j] = s_gi[rc] * s_ST[e * SROW + rc];
        }
        ((float4*)o2)[i4] = make_float4(q[0], q[1], q[2], q[3]);
        ((float4*)o1)[i4] = make_float4(f[0], f[1], f[2], f[3]);
        ((float4*)o0)[i4] = make_float4(f[0]+q[0], f[1]+q[1],
                                        f[2]+q[2], f[3]+q[3]);
    }
}

// ===========================================================================
extern "C" void kernel_launch(void* const* d_in, const int* in_sizes, int n_in,
                              void* d_out, int out_size, void* d_ws, size_t ws_size,
                              hipStream_t stream) {
    const float* Se = (const float*)d_in[0];
    const float* tt = (const float*)d_in[1];
    const float* pp = (const float*)d_in[2];
    float* out = (float*)d_out;

    int B = in_sizes[1] / T_LEN;

    constexpr int L = 16;
    constexpr int G = 8;
    constexpr int NSTEP = G * L;            // 128
    constexpr int TILES = T_LEN / NSTEP;    // 16

    unsigned* ticket = (unsigned*)d_ws;
    unsigned* flags  = ticket + 1;
    size_t ctl_bytes = (size_t)(1 + B * TILES) * sizeof(unsigned);
    size_t spine_off = (ctl_bytes + 15) & ~(size_t)15;
    float* spine = (float*)((char*)d_ws + spine_off);

    // reset ticket + flags each launch (graph-capturable)
    hipMemsetAsync(d_ws, 0, ctl_bytes, stream);

    fused<L, G><<<B * TILES, dim3(256), 0, stream>>>(
        Se, tt, pp, out, spine, flags, ticket, B);
}

// Round 2
// 124.899 us; speedup vs baseline: 2.3992x; 2.3992x over previous
//
#include <hip/hip_runtime.h>

#define T_LEN 2048
#define NMODE 8
#define NPP   17   // 8 tau + 9 g (g[0]=g_infy)

// ===========================================================================
// Fused single-kernel viscoelastic stress update — round 2.
//
// Same block decomposition as round 1 (one 128-step tile per block, G=8
// chunks x L=16). The inter-block protocol is rebuilt to avoid ALL L2
// cache-maintenance ops (the round-1 killer):
//   - spine payload: relaxed agent-scope atomic stores (write through to
//     the coherent point; no buffer_wbl2)
//   - ordering: per-wave s_waitcnt vmcnt(0) + __syncthreads, then a relaxed
//     agent-scope flag store (no release fence)
//   - lookback: wave 0 polls all <=15 predecessor flags IN PARALLEL with
//     relaxed agent loads (no buffer_inv), then 72 threads batch-load all
//     predecessor aggregates (30 independent loads, ~1 L3 latency) and
//     compose in registers.
// ===========================================================================
template <int L, int G>
__global__ __launch_bounds__(256)
void fused(const float* __restrict__ Se,   // [B,T,3,3]
           const float* __restrict__ tt,   // [B,T]
           const float* __restrict__ pp,   // [B,T,17]
           float* __restrict__ out,        // [3,B,T,3,3]
           float* __restrict__ spine,      // [B*TILES][80]  P[8] then R[72]
           unsigned* __restrict__ flags,   // [B*TILES]
           unsigned* __restrict__ ticket,
           int B) {
    constexpr int NSTEP = G * L;            // 128
    constexpr int TILES = T_LEN / NSTEP;    // 16
    constexpr int RW    = NSTEP + 1;        // 129
    constexpr int NT    = 256;
    constexpr int RAW_SZ = RW * NPP;                 // 2193
    constexpr int SROW   = NSTEP + 4;                // 132
    constexpr int QT_SZ  = 9 * SROW;                 // 1188
    constexpr int CA_K   = L * 8 + 4;                // 132
    constexpr int UNION_SZ = (RAW_SZ > QT_SZ + G * CA_K) ? RAW_SZ
                                                         : (QT_SZ + G * CA_K);
    constexpr int AC_K  = L * 16 + 4;                // 260
    constexpr int O_AC  = UNION_SZ;                  // AC | {Zrel,Pp,Z} overlay
    constexpr int O_RP  = O_AC + G * AC_K;           // s_R (576) + s_P (64)
    constexpr int O_ST  = O_RP + G * 72 + G * 8;
    constexpr int O_T   = O_ST + 9 * SROW;
    constexpr int O_INV = O_T + RW;
    constexpr int O_GI  = O_INV + RW;
    constexpr int TOTAL = O_GI + RW;
    static_assert(L == 16, "epilogue uses t>>4 / t&15");
    static_assert(G * 72 + G * 8 + G * 72 <= G * AC_K, "overlay fits in AC");

    __shared__ __align__(16) float sm[TOTAL];
    float* s_raw  = sm;                      // union: raw inputs
    float* s_qT   = sm;                      // union: qsum transposed [e][t]
    float* s_ca   = sm + QT_SZ;              // union: cumA skewed [k][s][8]
    float* s_AC   = sm + O_AC;               // coeffs (dead after phase 2)
    float* s_Zrel = sm + O_AC;               // overlay: chunk-relative prefix
    float* s_Pp   = sm + O_AC + G * 72;      // overlay: chunk prefix products
    float* s_Z    = sm + O_AC + G * 72 + G * 8;  // overlay: entering states
    float* s_R    = sm + O_RP;               // chunk-local results [k][e][m]
    float* s_P    = sm + O_RP + G * 72;      // chunk A-products   [k][m]
    float* s_ST   = sm + O_ST;
    float* s_t    = sm + O_T;
    float* s_inv  = sm + O_INV;
    float* s_gi   = sm + O_GI;

    const int tid = threadIdx.x;

    // ---- ticket: tile-major virtual id ----
    __shared__ unsigned s_vid;
    if (tid == 0) s_vid = atomicAdd(ticket, 1u);
    __syncthreads();
    const int vid  = (int)(s_vid % (unsigned)(B * TILES));
    const int tile = vid / B;     // all dependencies have strictly lower vid
    const int b    = vid % B;

    const int base = tile * NSTEP;
    const int off  = (base == 0) ? 0 : 1;
    const int r0   = (base == 0) ? 0 : base - 1;

    // ---- stage inputs ----
    {
        const float* pr = pp + ((size_t)b * T_LEN + r0) * NPP;
        for (int i = tid; i < RW * NPP; i += NT) s_raw[i] = pr[i];
        const float* sr = Se + ((size_t)b * T_LEN + r0) * 9;
        for (int i = tid; i < RW * 9; i += NT) {
            int r = i / 9, e = i - r * 9;
            s_ST[e * SROW + r] = sr[i];
        }
        const float* tr = tt + (size_t)b * T_LEN + r0;
        for (int i = tid; i < RW; i += NT) s_t[i] = tr[i];
    }
    __syncthreads();

    // ---- per-row 1/sum(g), g_infy/sum ----
    for (int i = tid; i < RW; i += NT) {
        float gs = 0.f;
        #pragma unroll
        for (int k = 8; k < NPP; ++k) gs += s_raw[i * NPP + k];
        float iv = __builtin_amdgcn_rcpf(gs);
        s_inv[i] = iv;
        s_gi[i]  = s_raw[i * NPP + 8] * iv;
    }
    __syncthreads();

    // ---- per-(step,mode) coefficients: all exp/rcp here ----
    for (int i = tid; i < NSTEP * 8; i += NT) {
        int m  = i & 7;
        int ts = i >> 3;
        int rc = ts + off;
        bool first = (base == 0) && (ts == 0);
        int rp = first ? rc : rc - 1;
        float tau_c = s_raw[rc * NPP + m];
        float tau_p = s_raw[rp * NPP + m];
        float gqh_c = 0.5f * s_raw[rc * NPP + 9 + m] * s_inv[rc];
        float gqh_p = 0.5f * s_raw[rp * NPP + 9 + m] * s_inv[rp];
        float t_c = s_t[rc];
        float t_p = first ? -s_t[1] : s_t[rp];
        float ee  = __expf((t_p - t_c) * __builtin_amdgcn_rcpf(tau_c + tau_p));
        int kk = ts / L, sl = ts % L;
        s_AC[kk * AC_K + sl * 16 + m]     = ee * ee;              // A
        s_AC[kk * AC_K + sl * 16 + 8 + m] = ee * (gqh_c + gqh_p); // C
    }
    __syncthreads();   // s_raw consumed; union becomes s_qT/s_ca

    // ---- phase 2: concurrent chunk scans + cumA ----
    if (tid < 72) {
        const int k = tid / 9;
        const int e = tid - k * 9;

        float dS[L];
        {
            float Sv[L + 1];
            Sv[0] = (base == 0 && k == 0)
                        ? 0.f
                        : s_ST[e * SROW + (k * L + off - 1)];
            #pragma unroll
            for (int s = 0; s < L; ++s)
                Sv[s + 1] = s_ST[e * SROW + (k * L + s + off)];
            #pragma unroll
            for (int s = 0; s < L; ++s) dS[s] = Sv[s + 1] - Sv[s];
        }

        float Q[8] = {0,0,0,0,0,0,0,0};
        const float4* acp = (const float4*)(s_AC + k * AC_K);

        float4 a0 = acp[0], a1 = acp[1], c0v = acp[2], c1v = acp[3];
        #pragma unroll
        for (int s = 0; s < L; ++s) {
            float4 na0, na1, nc0, nc1;
            if (s < L - 1) {
                na0 = acp[4*s+4]; na1 = acp[4*s+5];
                nc0 = acp[4*s+6]; nc1 = acp[4*s+7];
            }
            float d = dS[s];
            Q[0] = a0.x*Q[0] + c0v.x*d;  Q[1] = a0.y*Q[1] + c0v.y*d;
            Q[2] = a0.z*Q[2] + c0v.z*d;  Q[3] = a0.w*Q[3] + c0v.w*d;
            Q[4] = a1.x*Q[4] + c1v.x*d;  Q[5] = a1.y*Q[5] + c1v.y*d;
            Q[6] = a1.z*Q[6] + c1v.z*d;  Q[7] = a1.w*Q[7] + c1v.w*d;
            float qs = ((Q[0]+Q[1])+(Q[2]+Q[3])) + ((Q[4]+Q[5])+(Q[6]+Q[7]));
            s_qT[e * SROW + (k * L + s)] = qs;
            a0 = na0; a1 = na1; c0v = nc0; c1v = nc1;
        }

        float4* r4 = (float4*)(s_R + (k * 72 + e * 8));
        r4[0] = make_float4(Q[0], Q[1], Q[2], Q[3]);
        r4[1] = make_float4(Q[4], Q[5], Q[6], Q[7]);
    } else if (tid >= 192) {
        // ---- threads 192..255 = (k,m): cumA + chunk product ----
        const int u = tid - 192;
        const int k = u >> 3;
        const int m = u & 7;
        float c = 1.f;
        #pragma unroll
        for (int s = 0; s < L; ++s) {
            c *= s_AC[k * AC_K + s * 16 + m];
            s_ca[k * CA_K + s * 8 + m] = c;
        }
        s_P[u] = c;
    }
    __syncthreads();

    // ---- phase 3: in-block cross-chunk compose (72 threads = (e,m)) ----
    if (tid < 72) {
        const int e = tid >> 3;
        const int m = tid & 7;
        float z = 0.f, pprod = 1.f;
        #pragma unroll
        for (int k = 0; k < G; ++k) {
            s_Zrel[k * 72 + tid] = z;
            if (e == 0) s_Pp[k * 8 + m] = pprod;
            float Pk = s_P[k * 8 + m];
            z = Pk * z + s_R[k * 72 + tid];
            pprod *= Pk;
        }
        if (tile != TILES - 1) {   // last tile has no consumers
            float* sp = spine + ((size_t)b * TILES + tile) * 80;
            // relaxed agent stores: write through to coherent point, no wbl2
            __hip_atomic_store(sp + 8 + tid, z, __ATOMIC_RELAXED,
                               __HIP_MEMORY_SCOPE_AGENT);
            if (e == 0)
                __hip_atomic_store(sp + m, pprod, __ATOMIC_RELAXED,
                                   __HIP_MEMORY_SCOPE_AGENT);
        }
    }
    // drain each wave's own stores, then barrier -> all payload visible
    if (tile != TILES - 1)
        asm volatile("s_waitcnt vmcnt(0)" ::: "memory");
    __syncthreads();

    // ---- publish flag (relaxed: payload already at coherent point) ----
    if (tile != TILES - 1 && tid == 0)
        __hip_atomic_store(&flags[(size_t)b * TILES + tile], 1u,
                           __ATOMIC_RELAXED, __HIP_MEMORY_SCOPE_AGENT);

    // ---- phase 4: parallel lookback ----
    // wave 0: lane j polls flag j (relaxed, no cache maintenance)
    if (tid < 64) {
        bool done = (tid >= tile);
        while (!__all(done)) {
            if (!done) {
                unsigned f = __hip_atomic_load(
                    &flags[(size_t)b * TILES + tid],
                    __ATOMIC_RELAXED, __HIP_MEMORY_SCOPE_AGENT);
                done = (f != 0u);
                if (!done) __builtin_amdgcn_s_sleep(2);
            }
        }
    }
    __syncthreads();   // barrier orders flag observation before payload loads

    float zin = 0.f;
    if (tid < 72 && tile > 0) {
        const int m = tid & 7;
        const float* spb = spine + (size_t)b * TILES * 80;
        float Pv[TILES - 1], Rv[TILES - 1];
        #pragma unroll
        for (int j = 0; j < TILES - 1; ++j) {
            if (j < tile) {
                Pv[j] = __hip_atomic_load(spb + j * 80 + m,
                                          __ATOMIC_RELAXED,
                                          __HIP_MEMORY_SCOPE_AGENT);
                Rv[j] = __hip_atomic_load(spb + j * 80 + 8 + tid,
                                          __ATOMIC_RELAXED,
                                          __HIP_MEMORY_SCOPE_AGENT);
            }
        }
        #pragma unroll
        for (int j = 0; j < TILES - 1; ++j)
            if (j < tile) zin = Pv[j] * zin + Rv[j];
    }

    // ---- phase 5: entering state per chunk ----
    if (tid < 72) {
        const int m = tid & 7;
        #pragma unroll
        for (int k = 0; k < G; ++k)
            s_Z[k * 72 + tid] = s_Pp[k * 8 + m] * zin + s_Zrel[k * 72 + tid];
    }
    __syncthreads();

    // ---- phase 6: finalize all three planes, coalesced float4 ----
    const size_t nOut = (size_t)B * T_LEN * 9;
    float* o0 = out + ((size_t)b * T_LEN + base) * 9;
    float* o1 = o0 + nOut;
    float* o2 = o0 + 2 * nOut;
    for (int i4 = tid; i4 < NSTEP * 9 / 4; i4 += NT) {
        int i = i4 * 4;
        float q[4], f[4];
        #pragma unroll
        for (int j = 0; j < 4; ++j) {
            int idx = i + j;
            int t = idx / 9, e = idx - t * 9;
            int rc = t + off;
            int k = t >> 4, s = t & 15;
            const float* caT = &s_ca[k * CA_K + s * 8];
            const float* zE  = &s_Z[k * 72 + e * 8];
            float cr = 0.f;
            #pragma unroll
            for (int m = 0; m < NMODE; ++m) cr += caT[m] * zE[m];
            q[j] = s_qT[e * SROW + t] + cr;
            f[j] = s_gi[rc] * s_ST[e * SROW + rc];
        }
        ((float4*)o2)[i4] = make_float4(q[0], q[1], q[2], q[3]);
        ((float4*)o1)[i4] = make_float4(f[0], f[1], f[2], f[3]);
        ((float4*)o0)[i4] = make_float4(f[0]+q[0], f[1]+q[1],
                                        f[2]+q[2], f[3]+q[3]);
    }
}

// ===========================================================================
extern "C" void kernel_launch(void* const* d_in, const int* in_sizes, int n_in,
                              void* d_out, int out_size, void* d_ws, size_t ws_size,
                              hipStream_t stream) {
    const float* Se = (const float*)d_in[0];
    const float* tt = (const float*)d_in[1];
    const float* pp = (const float*)d_in[2];
    float* out = (float*)d_out;

    int B = in_sizes[1] / T_LEN;

    constexpr int L = 16;
    constexpr int G = 8;
    constexpr int NSTEP = G * L;            // 128
    constexpr int TILES = T_LEN / NSTEP;    // 16

    unsigned* ticket = (unsigned*)d_ws;
    unsigned* flags  = ticket + 1;
    size_t ctl_bytes = (size_t)(1 + B * TILES) * sizeof(unsigned);
    size_t spine_off = (ctl_bytes + 15) & ~(size_t)15;
    float* spine = (float*)((char*)d_ws + spine_off);

    // reset ticket + flags each launch (graph-capturable)
    hipMemsetAsync(d_ws, 0, ctl_bytes, stream);

    fused<L, G><<<B * TILES, dim3(256), 0, stream>>>(
        Se, tt, pp, out, spine, flags, ticket, B);
}

// Round 3
// 118.928 us; speedup vs baseline: 2.5197x; 1.0502x over previous
//
#include <hip/hip_runtime.h>

#define T_LEN 2048
#define NMODE 8
#define NPP   17   // 8 tau + 9 g (g[0]=g_infy)

// ===========================================================================
// Fused single-kernel viscoelastic stress update — round 3.
//
// Round-2 protocol (relaxed agent stores + vmcnt drain + relaxed flag,
// parallel flag poll, batched lookback) kept verbatim. This round targets
// FULL GRID RESIDENCY: 2048 blocks = 8 blocks/CU x 256 CU, which requires
// LDS <= 20480 B and VGPR <= 64:
//   - s_ST dropped: dS reads Se scattered from global (L2), epilogue reads
//     Se coalesced float4 (same layout as output planes).
//   - s_R/s_P overlaid into the dead A/C region (extra barrier separates
//     last AC read from R/P write).
//   - __launch_bounds__(256, 8) pins VGPR to 64.
//   - S_infy plane stores hoisted into the lookback wait window.
// LDS: 18844 B -> 8 blocks/CU; all blocks co-resident -> waits ~ 0.
// ===========================================================================
template <int L, int G>
__global__ __launch_bounds__(256, 8)
void fused(const float* __restrict__ Se,   // [B,T,3,3]
           const float* __restrict__ tt,   // [B,T]
           const float* __restrict__ pp,   // [B,T,17]
           float* __restrict__ out,        // [3,B,T,3,3]
           float* __restrict__ spine,      // [B*TILES][80]  P[8] then R[72]
           unsigned* __restrict__ flags,   // [B*TILES]
           unsigned* __restrict__ ticket,
           int B) {
    constexpr int NSTEP = G * L;            // 128
    constexpr int TILES = T_LEN / NSTEP;    // 16
    constexpr int RW    = NSTEP + 1;        // 129
    constexpr int NT    = 256;
    constexpr int RAW_SZ = RW * NPP;                 // 2193
    constexpr int SROW   = NSTEP + 4;                // 132
    constexpr int QT_SZ  = 9 * SROW;                 // 1188
    constexpr int CA_K   = L * 8 + 4;                // 132
    constexpr int UNION_SZ = (RAW_SZ > QT_SZ + G * CA_K) ? RAW_SZ
                                                         : (QT_SZ + G * CA_K);
    constexpr int AC_K  = L * 16 + 4;                // 260
    constexpr int O_AC  = UNION_SZ;                  // 2244
    // overlay inside the AC region (AC dead after phase 2):
    constexpr int OV_ZREL = 0;                       // G*72 = 576
    constexpr int OV_PP   = G * 72;                  // G*8  = 64
    constexpr int OV_Z    = OV_PP + G * 8;           // G*72 = 576
    constexpr int OV_R    = OV_Z + G * 72;           // G*72 = 576
    constexpr int OV_P    = OV_R + G * 72;           // G*8  = 64
    static_assert(OV_P + G * 8 <= G * AC_K, "overlay fits in AC region");
    constexpr int O_T   = O_AC + G * AC_K;           // 4324
    constexpr int O_INV = O_T + RW;
    constexpr int O_GI  = O_INV + RW;
    constexpr int TOTAL = O_GI + RW;                 // 4711 floats
    static_assert(TOTAL * 4 <= 20480, "LDS must allow 8 blocks/CU");
    static_assert(L == 16, "epilogue uses t>>4 / t&15");

    __shared__ __align__(16) float sm[TOTAL];
    float* s_raw  = sm;                      // union: raw inputs
    float* s_qT   = sm;                      // union: qsum transposed [e][t]
    float* s_ca   = sm + QT_SZ;              // union: cumA skewed [k][s][8]
    float* s_AC   = sm + O_AC;               // coeffs (dead after phase 2)
    float* s_Zrel = sm + O_AC + OV_ZREL;
    float* s_Pp   = sm + O_AC + OV_PP;
    float* s_Z    = sm + O_AC + OV_Z;
    float* s_R    = sm + O_AC + OV_R;
    float* s_P    = sm + O_AC + OV_P;
    float* s_t    = sm + O_T;
    float* s_inv  = sm + O_INV;
    float* s_gi   = sm + O_GI;

    const int tid = threadIdx.x;

    // ---- ticket: tile-major virtual id ----
    __shared__ unsigned s_vid;
    if (tid == 0) s_vid = atomicAdd(ticket, 1u);
    __syncthreads();
    const int vid  = (int)(s_vid % (unsigned)(B * TILES));
    const int tile = vid / B;     // all dependencies have strictly lower vid
    const int b    = vid % B;

    const int base = tile * NSTEP;
    const int off  = (base == 0) ? 0 : 1;
    const int r0   = (base == 0) ? 0 : base - 1;

    // ---- stage pp + t ----
    {
        const float* pr = pp + ((size_t)b * T_LEN + r0) * NPP;
        for (int i = tid; i < RW * NPP; i += NT) s_raw[i] = pr[i];
        const float* tr = tt + (size_t)b * T_LEN + r0;
        for (int i = tid; i < RW; i += NT) s_t[i] = tr[i];
    }
    __syncthreads();

    // ---- per-row 1/sum(g), g_infy/sum ----
    for (int i = tid; i < RW; i += NT) {
        float gs = 0.f;
        #pragma unroll
        for (int k = 8; k < NPP; ++k) gs += s_raw[i * NPP + k];
        float iv = __builtin_amdgcn_rcpf(gs);
        s_inv[i] = iv;
        s_gi[i]  = s_raw[i * NPP + 8] * iv;
    }
    __syncthreads();

    // ---- per-(step,mode) coefficients ----
    for (int i = tid; i < NSTEP * 8; i += NT) {
        int m  = i & 7;
        int ts = i >> 3;
        int rc = ts + off;
        bool first = (base == 0) && (ts == 0);
        int rp = first ? rc : rc - 1;
        float tau_c = s_raw[rc * NPP + m];
        float tau_p = s_raw[rp * NPP + m];
        float gqh_c = 0.5f * s_raw[rc * NPP + 9 + m] * s_inv[rc];
        float gqh_p = 0.5f * s_raw[rp * NPP + 9 + m] * s_inv[rp];
        float t_c = s_t[rc];
        float t_p = first ? -s_t[1] : s_t[rp];
        float ee  = __expf((t_p - t_c) * __builtin_amdgcn_rcpf(tau_c + tau_p));
        int kk = ts / L, sl = ts % L;
        s_AC[kk * AC_K + sl * 16 + m]     = ee * ee;              // A
        s_AC[kk * AC_K + sl * 16 + 8 + m] = ee * (gqh_c + gqh_p); // C
    }
    __syncthreads();   // s_raw consumed; union becomes s_qT/s_ca

    // ---- phase 2: chunk scans (tid<72) + cumA (tid>=192); results in regs ----
    float Q[8] = {0,0,0,0,0,0,0,0};
    float cumA_c = 1.f;
    if (tid < 72) {
        const int k = tid / 9;
        const int e = tid - k * 9;
        const float* Sg = Se + (size_t)b * T_LEN * 9 + e;
        const int gbase = base + k * L;

        float dS[L];
        {
            float prev = (base == 0 && k == 0) ? 0.f
                                               : Sg[(size_t)(gbase - 1) * 9];
            #pragma unroll
            for (int s = 0; s < L; ++s) {
                float cur = Sg[(size_t)(gbase + s) * 9];
                dS[s] = cur - prev;
                prev = cur;
            }
        }

        const float4* acp = (const float4*)(s_AC + k * AC_K);
        #pragma unroll
        for (int s = 0; s < L; ++s) {
            float4 a0 = acp[4*s], a1 = acp[4*s+1];
            float4 c0v = acp[4*s+2], c1v = acp[4*s+3];
            float d = dS[s];
            Q[0] = a0.x*Q[0] + c0v.x*d;  Q[1] = a0.y*Q[1] + c0v.y*d;
            Q[2] = a0.z*Q[2] + c0v.z*d;  Q[3] = a0.w*Q[3] + c0v.w*d;
            Q[4] = a1.x*Q[4] + c1v.x*d;  Q[5] = a1.y*Q[5] + c1v.y*d;
            Q[6] = a1.z*Q[6] + c1v.z*d;  Q[7] = a1.w*Q[7] + c1v.w*d;
            float qs = ((Q[0]+Q[1])+(Q[2]+Q[3])) + ((Q[4]+Q[5])+(Q[6]+Q[7]));
            s_qT[e * SROW + (k * L + s)] = qs;
        }
    } else if (tid >= 192) {
        const int u = tid - 192;
        const int k = u >> 3;
        const int m = u & 7;
        #pragma unroll
        for (int s = 0; s < L; ++s) {
            cumA_c *= s_AC[k * AC_K + s * 16 + m];
            s_ca[k * CA_K + s * 8 + m] = cumA_c;
        }
    }
    __syncthreads();   // last AC reads done -> overlay region now writable

    if (tid < 72) {
        float4* r4 = (float4*)(s_R + 8 * tid);   // k*72 + e*8 == 8*tid
        r4[0] = make_float4(Q[0], Q[1], Q[2], Q[3]);
        r4[1] = make_float4(Q[4], Q[5], Q[6], Q[7]);
    } else if (tid >= 192) {
        s_P[tid - 192] = cumA_c;
    }
    __syncthreads();

    // ---- phase 3: in-block cross-chunk compose (72 threads = (e,m)) ----
    if (tid < 72) {
        const int e = tid >> 3;
        const int m = tid & 7;
        float z = 0.f, pprod = 1.f;
        #pragma unroll
        for (int k = 0; k < G; ++k) {
            s_Zrel[k * 72 + tid] = z;
            if (e == 0) s_Pp[k * 8 + m] = pprod;
            float Pk = s_P[k * 8 + m];
            z = Pk * z + s_R[k * 72 + tid];
            pprod *= Pk;
        }
        if (tile != TILES - 1) {   // last tile has no consumers
            float* sp = spine + ((size_t)b * TILES + tile) * 80;
            __hip_atomic_store(sp + 8 + tid, z, __ATOMIC_RELAXED,
                               __HIP_MEMORY_SCOPE_AGENT);
            if (e == 0)
                __hip_atomic_store(sp + m, pprod, __ATOMIC_RELAXED,
                                   __HIP_MEMORY_SCOPE_AGENT);
        }
    }
    if (tile != TILES - 1)
        asm volatile("s_waitcnt vmcnt(0)" ::: "memory");
    __syncthreads();

    // ---- publish flag (payload already at coherent point) ----
    if (tile != TILES - 1 && tid == 0)
        __hip_atomic_store(&flags[(size_t)b * TILES + tile], 1u,
                           __ATOMIC_RELAXED, __HIP_MEMORY_SCOPE_AGENT);

    // ---- epilogue part A: S_infy plane (independent of lookback) ----
    const size_t nOut = (size_t)B * T_LEN * 9;
    float* o0 = out + ((size_t)b * T_LEN + base) * 9;
    float* o1 = o0 + nOut;
    float* o2 = o0 + 2 * nOut;
    const float4* sv4 = (const float4*)(Se + ((size_t)b * T_LEN + base) * 9);
    for (int i4 = tid; i4 < NSTEP * 9 / 4; i4 += NT) {
        float4 sv = sv4[i4];
        int i = i4 * 4;
        float f0 = s_gi[(i    ) / 9 + off] * sv.x;
        float f1 = s_gi[(i + 1) / 9 + off] * sv.y;
        float f2 = s_gi[(i + 2) / 9 + off] * sv.z;
        float f3 = s_gi[(i + 3) / 9 + off] * sv.w;
        ((float4*)o1)[i4] = make_float4(f0, f1, f2, f3);
    }

    // ---- phase 4: parallel lookback ----
    if (tile > 0 && tid < 64) {
        bool done = (tid >= tile);
        while (!__all(done)) {
            if (!done) {
                unsigned f = __hip_atomic_load(
                    &flags[(size_t)b * TILES + tid],
                    __ATOMIC_RELAXED, __HIP_MEMORY_SCOPE_AGENT);
                done = (f != 0u);
                if (!done) __builtin_amdgcn_s_sleep(1);
            }
        }
    }
    __syncthreads();   // flag observation ordered before payload loads

    float zin = 0.f;
    if (tid < 72 && tile > 0) {
        const int m = tid & 7;
        const float* spb = spine + (size_t)b * TILES * 80;
        float Pv[TILES - 1], Rv[TILES - 1];
        #pragma unroll
        for (int j = 0; j < TILES - 1; ++j) {
            if (j < tile) {
                Pv[j] = __hip_atomic_load(spb + j * 80 + m,
                                          __ATOMIC_RELAXED,
                                          __HIP_MEMORY_SCOPE_AGENT);
                Rv[j] = __hip_atomic_load(spb + j * 80 + 8 + tid,
                                          __ATOMIC_RELAXED,
                                          __HIP_MEMORY_SCOPE_AGENT);
            }
        }
        #pragma unroll
        for (int j = 0; j < TILES - 1; ++j)
            if (j < tile) zin = Pv[j] * zin + Rv[j];
    }

    // ---- phase 5: entering state per chunk ----
    if (tid < 72) {
        const int m = tid & 7;
        #pragma unroll
        for (int k = 0; k < G; ++k)
            s_Z[k * 72 + tid] = s_Pp[k * 8 + m] * zin + s_Zrel[k * 72 + tid];
    }
    __syncthreads();

    // ---- epilogue part B: S and Q_sum planes ----
    for (int i4 = tid; i4 < NSTEP * 9 / 4; i4 += NT) {
        float4 sv = sv4[i4];   // L1/L2-warm re-read
        const float svc[4] = {sv.x, sv.y, sv.z, sv.w};
        int i = i4 * 4;
        float q[4], f[4];
        #pragma unroll
        for (int j = 0; j < 4; ++j) {
            int idx = i + j;
            int t = idx / 9, e = idx - t * 9;
            int rc = t + off;
            int k = t >> 4, s = t & 15;
            const float* caT = &s_ca[k * CA_K + s * 8];
            const float* zE  = &s_Z[k * 72 + e * 8];
            float cr = 0.f;
            #pragma unroll
            for (int m = 0; m < NMODE; ++m) cr += caT[m] * zE[m];
            q[j] = s_qT[e * SROW + t] + cr;
            f[j] = s_gi[rc] * svc[j];
        }
        ((float4*)o2)[i4] = make_float4(q[0], q[1], q[2], q[3]);
        ((float4*)o0)[i4] = make_float4(f[0]+q[0], f[1]+q[1],
                                        f[2]+q[2], f[3]+q[3]);
    }
}

// ===========================================================================
extern "C" void kernel_launch(void* const* d_in, const int* in_sizes, int n_in,
                              void* d_out, int out_size, void* d_ws, size_t ws_size,
                              hipStream_t stream) {
    const float* Se = (const float*)d_in[0];
    const float* tt = (const float*)d_in[1];
    const float* pp = (const float*)d_in[2];
    float* out = (float*)d_out;

    int B = in_sizes[1] / T_LEN;

    constexpr int L = 16;
    constexpr int G = 8;
    constexpr int NSTEP = G * L;            // 128
    constexpr int TILES = T_LEN / NSTEP;    // 16

    unsigned* ticket = (unsigned*)d_ws;
    unsigned* flags  = ticket + 1;
    size_t ctl_bytes = (size_t)(1 + B * TILES) * sizeof(unsigned);
    size_t spine_off = (ctl_bytes + 15) & ~(size_t)15;
    float* spine = (float*)((char*)d_ws + spine_off);

    // reset ticket + flags each launch (graph-capturable)
    hipMemsetAsync(d_ws, 0, ctl_bytes, stream);

    fused<L, G><<<B * TILES, dim3(256), 0, stream>>>(
        Se, tt, pp, out, spine, flags, ticket, B);
}

// Round 4
// 118.797 us; speedup vs baseline: 2.5225x; 1.0011x over previous
//
#include <hip/hip_runtime.h>

#define T_LEN 2048
#define NMODE 8
#define NPP   17   // 8 tau + 9 g (g[0]=g_infy)

// ===========================================================================
// Fused single-kernel viscoelastic stress update — round 4.
//
// Round-3 structure and inter-block protocol kept (relaxed agent stores +
// vmcnt drain + relaxed flag; parallel poll; batched lookback). Changes:
//   - STRIPED tickets (8 counters): vid%8 == b%8, so each b's dependency
//     chain lives in one stripe; arrival-order insurance preserved, 8x less
//     same-address atomic serialization (was ~7us of start skew).
//   - pp/t staging dropped: inv+coeff read global directly (L1/L2-warm
//     8.8KB tile). One fewer phase + barrier, ~4.6k LDS ops saved.
//   - S_infy plane written by threads 72..191 DURING the scan phase
//     (they were idle); fully hidden behind the chunk scans.
//   - correction dot uses explicit float4 LDS loads (4x b128 per element
//     instead of 16x b32).
// LDS 18328 B, VGPR<=64 -> full 2048-block residency (8 blocks/CU).
// ===========================================================================
template <int L, int G>
__global__ __launch_bounds__(256, 8)
void fused(const float* __restrict__ Se,   // [B,T,3,3]
           const float* __restrict__ tt,   // [B,T]
           const float* __restrict__ pp,   // [B,T,17]
           float* __restrict__ out,        // [3,B,T,3,3]
           float* __restrict__ spine,      // [B*TILES][80]  P[8] then R[72]
           unsigned* __restrict__ flags,   // [B*TILES]
           unsigned* __restrict__ ticket,  // [8] striped
           int B) {
    constexpr int NSTEP = G * L;            // 128
    constexpr int TILES = T_LEN / NSTEP;    // 16
    constexpr int RW    = NSTEP + 1;        // 129
    constexpr int NT    = 256;
    constexpr int SROW  = NSTEP + 4;        // 132
    constexpr int QT_SZ = 9 * SROW;         // 1188
    constexpr int CA_K  = L * 8 + 4;        // 132
    constexpr int AC_K  = L * 16 + 4;       // 260
    constexpr int O_AC  = QT_SZ + G * CA_K; // 2244
    // overlay inside AC region (AC dead after scan phase):
    constexpr int OV_ZREL = 0;                   // G*72 = 576
    constexpr int OV_PP   = G * 72;              // G*8  = 64
    constexpr int OV_Z    = OV_PP + G * 8;       // G*72 = 576
    constexpr int OV_R    = OV_Z + G * 72;       // G*72 = 576
    constexpr int OV_P    = OV_R + G * 72;       // G*8  = 64
    static_assert(OV_P + G * 8 <= G * AC_K, "overlay fits in AC region");
    constexpr int O_INV = O_AC + G * AC_K;       // 4324
    constexpr int O_GI  = O_INV + RW;            // 4453
    constexpr int TOTAL = O_GI + RW;             // 4582 floats = 18328 B
    static_assert(TOTAL * 4 <= 20480, "LDS must allow 8 blocks/CU");
    static_assert(L == 16, "epilogue uses t>>4 / t&15");

    __shared__ __align__(16) float sm[TOTAL];
    float* s_qT   = sm;                      // qsum transposed [e][t]
    float* s_ca   = sm + QT_SZ;              // cumA skewed [k][s][8]
    float* s_AC   = sm + O_AC;               // coeffs (dead after scan)
    float* s_Zrel = sm + O_AC + OV_ZREL;
    float* s_Pp   = sm + O_AC + OV_PP;
    float* s_Z    = sm + O_AC + OV_Z;
    float* s_R    = sm + O_AC + OV_R;
    float* s_P    = sm + O_AC + OV_P;
    float* s_inv  = sm + O_INV;
    float* s_gi   = sm + O_GI;

    const int tid = threadIdx.x;

    // ---- striped ticket: tile-major virtual id ----
    __shared__ unsigned s_vid;
    if (tid == 0) {
        unsigned stripe = (unsigned)blockIdx.x & 7u;
        unsigned idx = atomicAdd(&ticket[stripe], 1u);
        s_vid = idx * 8u + stripe;
    }
    __syncthreads();
    const int vid  = (int)(s_vid % (unsigned)(B * TILES));
    const int tile = vid / B;     // deps have strictly lower vid, same stripe
    const int b    = vid % B;

    const int base = tile * NSTEP;
    const int off  = (base == 0) ? 0 : 1;
    const int r0   = (base == 0) ? 0 : base - 1;

    const float* ppb = pp + ((size_t)b * T_LEN + r0) * NPP;
    const float* ttb = tt + (size_t)b * T_LEN + r0;

    // ---- per-row 1/sum(g), g_infy/sum (global reads, no staging) ----
    for (int i = tid; i < RW; i += NT) {
        const float* gp = ppb + i * NPP + 8;
        float gs = 0.f;
        #pragma unroll
        for (int k = 0; k < 9; ++k) gs += gp[k];
        float iv = __builtin_amdgcn_rcpf(gs);
        s_inv[i] = iv;
        s_gi[i]  = gp[0] * iv;
    }
    __syncthreads();

    // ---- per-(step,mode) coefficients (global reads, L1/L2-warm) ----
    for (int i = tid; i < NSTEP * 8; i += NT) {
        int m  = i & 7;
        int ts = i >> 3;
        int rc = ts + off;
        bool first = (base == 0) && (ts == 0);
        int rp = first ? rc : rc - 1;
        float tau_c = ppb[rc * NPP + m];
        float tau_p = ppb[rp * NPP + m];
        float gqh_c = 0.5f * ppb[rc * NPP + 9 + m] * s_inv[rc];
        float gqh_p = 0.5f * ppb[rp * NPP + 9 + m] * s_inv[rp];
        float t_c = ttb[rc];
        float t_p = first ? -ttb[1] : ttb[rp];
        float ee  = __expf((t_p - t_c) * __builtin_amdgcn_rcpf(tau_c + tau_p));
        int kk = ts / L, sl = ts % L;
        s_AC[kk * AC_K + sl * 16 + m]     = ee * ee;              // A
        s_AC[kk * AC_K + sl * 16 + 8 + m] = ee * (gqh_c + gqh_p); // C
    }
    __syncthreads();

    const size_t nOut = (size_t)B * T_LEN * 9;
    float* o0 = out + ((size_t)b * T_LEN + base) * 9;
    float* o1 = o0 + nOut;
    float* o2 = o0 + 2 * nOut;
    const float4* sv4 = (const float4*)(Se + ((size_t)b * T_LEN + base) * 9);

    // ---- scan phase: chunk scans (tid<72) | S_infy plane (72..191)
    //                  | cumA (192..255) ----
    float Q[8] = {0,0,0,0,0,0,0,0};
    float cumA_c = 1.f;
    if (tid < 72) {
        const int k = tid / 9;
        const int e = tid - k * 9;
        const float* Sg = Se + (size_t)b * T_LEN * 9 + e;
        const int gbase = base + k * L;

        float dS[L];
        {
            float prev = (base == 0 && k == 0) ? 0.f
                                               : Sg[(size_t)(gbase - 1) * 9];
            #pragma unroll
            for (int s = 0; s < L; ++s) {
                float cur = Sg[(size_t)(gbase + s) * 9];
                dS[s] = cur - prev;
                prev = cur;
            }
        }

        const float4* acp = (const float4*)(s_AC + k * AC_K);
        #pragma unroll
        for (int s = 0; s < L; ++s) {
            float4 a0 = acp[4*s], a1 = acp[4*s+1];
            float4 c0v = acp[4*s+2], c1v = acp[4*s+3];
            float d = dS[s];
            Q[0] = a0.x*Q[0] + c0v.x*d;  Q[1] = a0.y*Q[1] + c0v.y*d;
            Q[2] = a0.z*Q[2] + c0v.z*d;  Q[3] = a0.w*Q[3] + c0v.w*d;
            Q[4] = a1.x*Q[4] + c1v.x*d;  Q[5] = a1.y*Q[5] + c1v.y*d;
            Q[6] = a1.z*Q[6] + c1v.z*d;  Q[7] = a1.w*Q[7] + c1v.w*d;
            float qs = ((Q[0]+Q[1])+(Q[2]+Q[3])) + ((Q[4]+Q[5])+(Q[6]+Q[7]));
            s_qT[e * SROW + (k * L + s)] = qs;
        }
    } else if (tid < 192) {
        // S_infy plane — independent of scan/lookback, hidden here
        for (int i4 = tid - 72; i4 < NSTEP * 9 / 4; i4 += 120) {
            float4 sv = sv4[i4];
            int i = i4 * 4;
            float f0 = s_gi[(i    ) / 9 + off] * sv.x;
            float f1 = s_gi[(i + 1) / 9 + off] * sv.y;
            float f2 = s_gi[(i + 2) / 9 + off] * sv.z;
            float f3 = s_gi[(i + 3) / 9 + off] * sv.w;
            ((float4*)o1)[i4] = make_float4(f0, f1, f2, f3);
        }
    } else {
        const int u = tid - 192;
        const int k = u >> 3;
        const int m = u & 7;
        #pragma unroll
        for (int s = 0; s < L; ++s) {
            cumA_c *= s_AC[k * AC_K + s * 16 + m];
            s_ca[k * CA_K + s * 8 + m] = cumA_c;
        }
    }
    __syncthreads();   // last AC reads done -> overlay region now writable

    if (tid < 72) {
        float4* r4 = (float4*)(s_R + 8 * tid);   // k*72 + e*8 == 8*tid
        r4[0] = make_float4(Q[0], Q[1], Q[2], Q[3]);
        r4[1] = make_float4(Q[4], Q[5], Q[6], Q[7]);
    } else if (tid >= 192) {
        s_P[tid - 192] = cumA_c;
    }
    __syncthreads();

    // ---- compose across chunks (72 threads = (e,m)) + spine publish ----
    if (tid < 72) {
        const int e = tid >> 3;
        const int m = tid & 7;
        float z = 0.f, pprod = 1.f;
        #pragma unroll
        for (int k = 0; k < G; ++k) {
            s_Zrel[k * 72 + tid] = z;
            if (e == 0) s_Pp[k * 8 + m] = pprod;
            float Pk = s_P[k * 8 + m];
            z = Pk * z + s_R[k * 72 + tid];
            pprod *= Pk;
        }
        if (tile != TILES - 1) {   // last tile has no consumers
            float* sp = spine + ((size_t)b * TILES + tile) * 80;
            __hip_atomic_store(sp + 8 + tid, z, __ATOMIC_RELAXED,
                               __HIP_MEMORY_SCOPE_AGENT);
            if (e == 0)
                __hip_atomic_store(sp + m, pprod, __ATOMIC_RELAXED,
                                   __HIP_MEMORY_SCOPE_AGENT);
        }
    }
    if (tile != TILES - 1)
        asm volatile("s_waitcnt vmcnt(0)" ::: "memory");
    __syncthreads();

    // ---- publish flag (payload already at coherent point) ----
    if (tile != TILES - 1 && tid == 0)
        __hip_atomic_store(&flags[(size_t)b * TILES + tile], 1u,
                           __ATOMIC_RELAXED, __HIP_MEMORY_SCOPE_AGENT);

    // ---- parallel lookback ----
    if (tile > 0 && tid < 64) {
        bool done = (tid >= tile);
        while (!__all(done)) {
            if (!done) {
                unsigned f = __hip_atomic_load(
                    &flags[(size_t)b * TILES + tid],
                    __ATOMIC_RELAXED, __HIP_MEMORY_SCOPE_AGENT);
                done = (f != 0u);
                if (!done) __builtin_amdgcn_s_sleep(1);
            }
        }
    }
    __syncthreads();   // flag observation ordered before payload loads

    float zin = 0.f;
    if (tid < 72 && tile > 0) {
        const int m = tid & 7;
        const float* spb = spine + (size_t)b * TILES * 80;
        float Pv[TILES - 1], Rv[TILES - 1];
        #pragma unroll
        for (int j = 0; j < TILES - 1; ++j) {
            if (j < tile) {
                Pv[j] = __hip_atomic_load(spb + j * 80 + m,
                                          __ATOMIC_RELAXED,
                                          __HIP_MEMORY_SCOPE_AGENT);
                Rv[j] = __hip_atomic_load(spb + j * 80 + 8 + tid,
                                          __ATOMIC_RELAXED,
                                          __HIP_MEMORY_SCOPE_AGENT);
            }
        }
        #pragma unroll
        for (int j = 0; j < TILES - 1; ++j)
            if (j < tile) zin = Pv[j] * zin + Rv[j];
    }

    // ---- entering state per chunk ----
    if (tid < 72) {
        const int m = tid & 7;
        #pragma unroll
        for (int k = 0; k < G; ++k)
            s_Z[k * 72 + tid] = s_Pp[k * 8 + m] * zin + s_Zrel[k * 72 + tid];
    }
    __syncthreads();

    // ---- epilogue: S and Q_sum planes (float4 dot loads) ----
    for (int i4 = tid; i4 < NSTEP * 9 / 4; i4 += NT) {
        float4 sv = sv4[i4];   // L1/L2-warm re-read
        const float svc[4] = {sv.x, sv.y, sv.z, sv.w};
        int i = i4 * 4;
        float q[4], f[4];
        #pragma unroll
        for (int j = 0; j < 4; ++j) {
            int idx = i + j;
            int t = idx / 9, e = idx - t * 9;
            int rc = t + off;
            int k = t >> 4, s = t & 15;
            const float4* ca4 = (const float4*)(s_ca + k * CA_K + s * 8);
            const float4* z4  = (const float4*)(s_Z + k * 72 + e * 8);
            float4 cA = ca4[0], cB = ca4[1];
            float4 zA = z4[0],  zB = z4[1];
            float cr = ((cA.x*zA.x + cA.y*zA.y) + (cA.z*zA.z + cA.w*zA.w))
                     + ((cB.x*zB.x + cB.y*zB.y) + (cB.z*zB.z + cB.w*zB.w));
            q[j] = s_qT[e * SROW + t] + cr;
            f[j] = s_gi[rc] * svc[j];
        }
        ((float4*)o2)[i4] = make_float4(q[0], q[1], q[2], q[3]);
        ((float4*)o0)[i4] = make_float4(f[0]+q[0], f[1]+q[1],
                                        f[2]+q[2], f[3]+q[3]);
    }
}

// ===========================================================================
extern "C" void kernel_launch(void* const* d_in, const int* in_sizes, int n_in,
                              void* d_out, int out_size, void* d_ws, size_t ws_size,
                              hipStream_t stream) {
    const float* Se = (const float*)d_in[0];
    const float* tt = (const float*)d_in[1];
    const float* pp = (const float*)d_in[2];
    float* out = (float*)d_out;

    int B = in_sizes[1] / T_LEN;

    constexpr int L = 16;
    constexpr int G = 8;
    constexpr int NSTEP = G * L;            // 128
    constexpr int TILES = T_LEN / NSTEP;    // 16

    unsigned* ticket = (unsigned*)d_ws;            // [8] striped
    unsigned* flags  = ticket + 8;
    size_t ctl_bytes = (size_t)(8 + B * TILES) * sizeof(unsigned);
    size_t spine_off = (ctl_bytes + 15) & ~(size_t)15;
    float* spine = (float*)((char*)d_ws + spine_off);

    // reset tickets + flags each launch (graph-capturable)
    hipMemsetAsync(d_ws, 0, ctl_bytes, stream);

    fused<L, G><<<B * TILES, dim3(256), 0, stream>>>(
        Se, tt, pp, out, spine, flags, ticket, B);
}

// Round 5
// 98.412 us; speedup vs baseline: 3.0450x; 1.2071x over previous
//
#include <hip/hip_runtime.h>

#define T_LEN 2048
#define NMODE 8
#define NPP   17   // 8 tau + 9 g (g[0]=g_infy)

// ===========================================================================
// Round 5: waitless 2-kernel pipeline (fused in-kernel protocol refuted by
// R1-R4 data: 3-kernel round-0 did the work in ~38us kernel-time vs fused 47).
//
// scanK (grid B*TILES): per 128-step tile: coeff pass -> chunk scans ->
//   in-block compose; writes S_infy plane, TILE-LOCALLY-CORRECTED q plane
//   (in-tile Zrel folded into the epilogue dot), tile-folded cumA
//   caT[t,m] = Pp[k,m]*ca[k][s,m], and per-tile aggregates (P[8],R[72]).
// finishK (grid B*TILES): batch-load <=15 predecessor aggregates (one
//   latency, predicated unroll), 15-FMA spine fold in registers (this IS
//   old phaseB), then stream corr = caT[t] . Ztile_in[e] into S / Q_sum.
//
// No atomics, no flags, no memset, no waits. Kernel1 keeps all round-4
// front-end wins: no pp/t staging, S_infy hidden in scan phase, 18.3KB LDS
// -> 8 blocks/CU (round-0 phaseA had 26.6KB -> 6/CU).
// ===========================================================================
template <int L, int G>
__global__ __launch_bounds__(256, 8)
void scanK(const float* __restrict__ Se,   // [B,T,3,3]
           const float* __restrict__ tt,   // [B,T]
           const float* __restrict__ pp,   // [B,T,17]
           float* __restrict__ out,        // [3,B,T,3,3]
           float* __restrict__ caT,        // [B,T,8] tile-folded cumA
           float* __restrict__ agg,        // [B*TILES][80] P[8] then R[72]
           int B) {
    constexpr int NSTEP = G * L;            // 128
    constexpr int TILES = T_LEN / NSTEP;    // 16
    constexpr int RW    = NSTEP + 1;        // 129
    constexpr int NT    = 256;
    constexpr int SROW  = NSTEP + 4;        // 132
    constexpr int QT_SZ = 9 * SROW;         // 1188
    constexpr int CA_K  = L * 8 + 4;        // 132
    constexpr int AC_K  = L * 16 + 4;       // 260
    constexpr int O_AC  = QT_SZ + G * CA_K; // 2244
    // overlay inside AC region (AC dead after scan phase):
    constexpr int OV_ZREL = 0;                   // G*72 = 576
    constexpr int OV_PP   = G * 72;              // G*8  = 64
    constexpr int OV_R    = OV_PP + G * 8;       // G*72 = 576
    constexpr int OV_P    = OV_R + G * 72;       // G*8  = 64
    static_assert(OV_P + G * 8 <= G * AC_K, "overlay fits in AC region");
    constexpr int O_INV = O_AC + G * AC_K;       // 4324
    constexpr int O_GI  = O_INV + RW;            // 4453
    constexpr int TOTAL = O_GI + RW;             // 4582 floats = 18328 B
    static_assert(TOTAL * 4 <= 20480, "LDS must allow 8 blocks/CU");
    static_assert(L == 16, "epilogue uses t>>4 / t&15");

    __shared__ __align__(16) float sm[TOTAL];
    float* s_qT   = sm;                      // qsum transposed [e][t]
    float* s_ca   = sm + QT_SZ;              // cumA skewed [k][s][8]
    float* s_AC   = sm + O_AC;               // coeffs (dead after scan)
    float* s_Zrel = sm + O_AC + OV_ZREL;
    float* s_Pp   = sm + O_AC + OV_PP;
    float* s_R    = sm + O_AC + OV_R;
    float* s_P    = sm + O_AC + OV_P;
    float* s_inv  = sm + O_INV;
    float* s_gi   = sm + O_GI;

    const int tid = threadIdx.x;
    const int b    = blockIdx.x / TILES;
    const int tile = blockIdx.x % TILES;

    const int base = tile * NSTEP;
    const int off  = (base == 0) ? 0 : 1;
    const int r0   = (base == 0) ? 0 : base - 1;

    const float* ppb = pp + ((size_t)b * T_LEN + r0) * NPP;
    const float* ttb = tt + (size_t)b * T_LEN + r0;

    // ---- per-row 1/sum(g), g_infy/sum (global reads) ----
    for (int i = tid; i < RW; i += NT) {
        const float* gp = ppb + i * NPP + 8;
        float gs = 0.f;
        #pragma unroll
        for (int k = 0; k < 9; ++k) gs += gp[k];
        float iv = __builtin_amdgcn_rcpf(gs);
        s_inv[i] = iv;
        s_gi[i]  = gp[0] * iv;
    }
    __syncthreads();

    // ---- per-(step,mode) coefficients (global reads, L1/L2-warm) ----
    for (int i = tid; i < NSTEP * 8; i += NT) {
        int m  = i & 7;
        int ts = i >> 3;
        int rc = ts + off;
        bool first = (base == 0) && (ts == 0);
        int rp = first ? rc : rc - 1;
        float tau_c = ppb[rc * NPP + m];
        float tau_p = ppb[rp * NPP + m];
        float gqh_c = 0.5f * ppb[rc * NPP + 9 + m] * s_inv[rc];
        float gqh_p = 0.5f * ppb[rp * NPP + 9 + m] * s_inv[rp];
        float t_c = ttb[rc];
        float t_p = first ? -ttb[1] : ttb[rp];
        float ee  = __expf((t_p - t_c) * __builtin_amdgcn_rcpf(tau_c + tau_p));
        int kk = ts / L, sl = ts % L;
        s_AC[kk * AC_K + sl * 16 + m]     = ee * ee;              // A
        s_AC[kk * AC_K + sl * 16 + 8 + m] = ee * (gqh_c + gqh_p); // C
    }
    __syncthreads();

    const size_t nOut = (size_t)B * T_LEN * 9;
    float* o1 = out + nOut + ((size_t)b * T_LEN + base) * 9;
    float* o2 = out + 2 * nOut + ((size_t)b * T_LEN + base) * 9;
    const float4* sv4 = (const float4*)(Se + ((size_t)b * T_LEN + base) * 9);

    // ---- scan phase: chunk scans (tid<72) | S_infy plane (72..191)
    //                  | cumA (192..255) ----
    float Q[8] = {0,0,0,0,0,0,0,0};
    float cumA_c = 1.f;
    if (tid < 72) {
        const int k = tid / 9;
        const int e = tid - k * 9;
        const float* Sg = Se + (size_t)b * T_LEN * 9 + e;
        const int gbase = base + k * L;

        float dS[L];
        {
            float prev = (base == 0 && k == 0) ? 0.f
                                               : Sg[(size_t)(gbase - 1) * 9];
            #pragma unroll
            for (int s = 0; s < L; ++s) {
                float cur = Sg[(size_t)(gbase + s) * 9];
                dS[s] = cur - prev;
                prev = cur;
            }
        }

        const float4* acp = (const float4*)(s_AC + k * AC_K);
        #pragma unroll
        for (int s = 0; s < L; ++s) {
            float4 a0 = acp[4*s], a1 = acp[4*s+1];
            float4 c0v = acp[4*s+2], c1v = acp[4*s+3];
            float d = dS[s];
            Q[0] = a0.x*Q[0] + c0v.x*d;  Q[1] = a0.y*Q[1] + c0v.y*d;
            Q[2] = a0.z*Q[2] + c0v.z*d;  Q[3] = a0.w*Q[3] + c0v.w*d;
            Q[4] = a1.x*Q[4] + c1v.x*d;  Q[5] = a1.y*Q[5] + c1v.y*d;
            Q[6] = a1.z*Q[6] + c1v.z*d;  Q[7] = a1.w*Q[7] + c1v.w*d;
            float qs = ((Q[0]+Q[1])+(Q[2]+Q[3])) + ((Q[4]+Q[5])+(Q[6]+Q[7]));
            s_qT[e * SROW + (k * L + s)] = qs;
        }
    } else if (tid < 192) {
        // S_infy plane — hidden behind the chunk scans
        for (int i4 = tid - 72; i4 < NSTEP * 9 / 4; i4 += 120) {
            float4 sv = sv4[i4];
            int i = i4 * 4;
            float f0 = s_gi[(i    ) / 9 + off] * sv.x;
            float f1 = s_gi[(i + 1) / 9 + off] * sv.y;
            float f2 = s_gi[(i + 2) / 9 + off] * sv.z;
            float f3 = s_gi[(i + 3) / 9 + off] * sv.w;
            ((float4*)o1)[i4] = make_float4(f0, f1, f2, f3);
        }
    } else {
        const int u = tid - 192;
        const int k = u >> 3;
        const int m = u & 7;
        #pragma unroll
        for (int s = 0; s < L; ++s) {
            cumA_c *= s_AC[k * AC_K + s * 16 + m];
            s_ca[k * CA_K + s * 8 + m] = cumA_c;
        }
    }
    __syncthreads();   // last AC reads done -> overlay region now writable

    if (tid < 72) {
        float4* r4 = (float4*)(s_R + 8 * tid);   // k*72 + e*8 == 8*tid
        r4[0] = make_float4(Q[0], Q[1], Q[2], Q[3]);
        r4[1] = make_float4(Q[4], Q[5], Q[6], Q[7]);
    } else if (tid >= 192) {
        s_P[tid - 192] = cumA_c;
    }
    __syncthreads();

    // ---- compose across chunks (72 threads = (e,m)); write aggregates ----
    if (tid < 72) {
        const int e = tid >> 3;
        const int m = tid & 7;
        float z = 0.f, pprod = 1.f;
        #pragma unroll
        for (int k = 0; k < G; ++k) {
            s_Zrel[k * 72 + tid] = z;
            if (e == 0) s_Pp[k * 8 + m] = pprod;
            float Pk = s_P[k * 8 + m];
            z = Pk * z + s_R[k * 72 + tid];
            pprod *= Pk;
        }
        if (tile != TILES - 1) {   // last tile has no consumers
            float* ap = agg + ((size_t)b * TILES + tile) * 80;
            ap[8 + tid] = z;
            if (e == 0) ap[m] = pprod;
        }
    }
    __syncthreads();

    // ---- tile-folded cumA: caT[t,m] = Pp[k,m] * ca[k][s,m] ----
    {
        int k = tid >> 5;           // 0..7
        int s = (tid >> 1) & 15;    // 0..15
        int h = tid & 1;            // 0..1
        float4 cv = *(const float4*)(s_ca + k * CA_K + s * 8 + h * 4);
        float4 pv = *(const float4*)(s_Pp + k * 8 + h * 4);
        float4 ov = make_float4(cv.x*pv.x, cv.y*pv.y, cv.z*pv.z, cv.w*pv.w);
        *(float4*)(caT + (((size_t)b * T_LEN + base) + k * L + s) * 8 + h * 4)
            = ov;
    }

    // ---- epilogue: q plane with IN-TILE correction folded (zin = 0) ----
    for (int i4 = tid; i4 < NSTEP * 9 / 4; i4 += NT) {
        int i = i4 * 4;
        float q[4];
        #pragma unroll
        for (int j = 0; j < 4; ++j) {
            int idx = i + j;
            int t = idx / 9, e = idx - t * 9;
            int k = t >> 4, s = t & 15;
            const float4* ca4 = (const float4*)(s_ca + k * CA_K + s * 8);
            const float4* z4  = (const float4*)(s_Zrel + k * 72 + e * 8);
            float4 cA = ca4[0], cB = ca4[1];
            float4 zA = z4[0],  zB = z4[1];
            float cr = ((cA.x*zA.x + cA.y*zA.y) + (cA.z*zA.z + cA.w*zA.w))
                     + ((cB.x*zB.x + cB.y*zB.y) + (cB.z*zB.z + cB.w*zB.w));
            q[j] = s_qT[e * SROW + t] + cr;
        }
        ((float4*)o2)[i4] = make_float4(q[0], q[1], q[2], q[3]);
    }
}

// ===========================================================================
// finishK: spine fold (old phaseB, now 15 in-register FMAs) + correction
// stream (old phaseC). One block per tile.
// ===========================================================================
template <int L, int G>
__global__ __launch_bounds__(256, 8)
void finishK(float* __restrict__ out,
             const float* __restrict__ caT,   // [B,T,8]
             const float* __restrict__ agg,   // [B*TILES][80]
             int B) {
    constexpr int NSTEP = G * L;            // 128
    constexpr int TILES = T_LEN / NSTEP;    // 16
    constexpr int NT    = 256;

    __shared__ __align__(16) float s_Z[80];
    __shared__ __align__(16) float s_ca[NSTEP * 8];

    const int tid  = threadIdx.x;
    const int b    = blockIdx.x / TILES;
    const int tile = blockIdx.x % TILES;
    const int base = tile * NSTEP;

    // stage tile-folded cumA (coalesced float4)
    {
        const float4* c4 = (const float4*)(caT + ((size_t)b * T_LEN + base) * 8);
        for (int i = tid; i < NSTEP * 8 / 4; i += NT)
            ((float4*)s_ca)[i] = c4[i];
    }

    // spine fold: batched predicated loads (one latency), 15 serial FMAs
    if (tid < 72) {
        const int m = tid & 7;
        float zin = 0.f;
        if (tile > 0) {
            const float* ab = agg + (size_t)b * TILES * 80;
            float Pv[TILES - 1], Rv[TILES - 1];
            #pragma unroll
            for (int j = 0; j < TILES - 1; ++j) {
                if (j < tile) {
                    Pv[j] = ab[j * 80 + m];
                    Rv[j] = ab[j * 80 + 8 + tid];
                }
            }
            #pragma unroll
            for (int j = 0; j < TILES - 1; ++j)
                if (j < tile) zin = Pv[j] * zin + Rv[j];
        }
        s_Z[tid] = zin;
    }
    __syncthreads();

    // correction stream: S = S_infy + (q_local + corr); Q_sum = q_local + corr
    const size_t nOut = (size_t)B * T_LEN * 9;
    float* o0 = out + ((size_t)b * T_LEN + base) * 9;
    const float4* sf4 = (const float4*)(o0 + nOut);
    float4* s4 = (float4*)o0;
    float4* q4 = (float4*)(o0 + 2 * nOut);

    for (int i4 = tid; i4 < NSTEP * 9 / 4; i4 += NT) {
        float4 qv = q4[i4];
        float4 fv = sf4[i4];
        int i = i4 * 4;
        float corr[4];
        #pragma unroll
        for (int j = 0; j < 4; ++j) {
            int idx = i + j;
            int t = idx / 9, e = idx - t * 9;
            const float4* ca4 = (const float4*)(s_ca + t * 8);
            const float4* z4  = (const float4*)(s_Z + e * 8);
            float4 cA = ca4[0], cB = ca4[1];
            float4 zA = z4[0],  zB = z4[1];
            corr[j] = ((cA.x*zA.x + cA.y*zA.y) + (cA.z*zA.z + cA.w*zA.w))
                    + ((cB.x*zB.x + cB.y*zB.y) + (cB.z*zB.z + cB.w*zB.w));
        }
        float4 qn = make_float4(qv.x + corr[0], qv.y + corr[1],
                                qv.z + corr[2], qv.w + corr[3]);
        q4[i4] = qn;
        s4[i4] = make_float4(fv.x + qn.x, fv.y + qn.y,
                             fv.z + qn.z, fv.w + qn.w);
    }
}

// ===========================================================================
extern "C" void kernel_launch(void* const* d_in, const int* in_sizes, int n_in,
                              void* d_out, int out_size, void* d_ws, size_t ws_size,
                              hipStream_t stream) {
    const float* Se = (const float*)d_in[0];
    const float* tt = (const float*)d_in[1];
    const float* pp = (const float*)d_in[2];
    float* out = (float*)d_out;

    int B = in_sizes[1] / T_LEN;

    constexpr int L = 16;
    constexpr int G = 8;
    constexpr int NSTEP = G * L;            // 128
    constexpr int TILES = T_LEN / NSTEP;    // 16

    float* caT = (float*)d_ws;                              // B*T*8 floats
    float* agg = caT + (size_t)B * T_LEN * 8;               // B*TILES*80

    scanK<L, G><<<B * TILES, dim3(256), 0, stream>>>(
        Se, tt, pp, out, caT, agg, B);
    finishK<L, G><<<B * TILES, dim3(256), 0, stream>>>(
        out, caT, agg, B);
}